// Round 4
// baseline (879.433 us; speedup 1.0000x reference)
//
#include <hip/hip_runtime.h>

#define N_NODES   100000
#define N_EDGES   3200000
#define F_IN      256
#define HID       16
#define NCLS      40

#define BSHIFT    6                                   // 64 nodes per bucket
#define NBUCK     ((N_NODES + 63) >> BSHIFT)          // 1563
#define CAP       2560                                // mean 2048, +11 sigma

// ---------------- phase 1: bin edges by coarse dst bucket ----------------
// pack: (dst & 63) << 20 | src   (src < 2^17)
__global__ void bin_kernel(const int* __restrict__ ei, int* __restrict__ bucket_cnt,
                           int* __restrict__ buf) {
    int e = blockIdx.x * blockDim.x + threadIdx.x;
    if (e >= N_EDGES) return;
    int d = ei[N_EDGES + e];
    int s = ei[e];
    int b = d >> BSHIFT;
    int pos = atomicAdd(&bucket_cnt[b], 1);
    if (pos < CAP) buf[b * CAP + pos] = ((d & 63) << 20) | s;
}

// ---------------- phase 2: exclusive scan of 1563 bucket counts ----------------
__global__ __launch_bounds__(1024) void bscan_kernel(const int* __restrict__ bucket_cnt,
                                                     int* __restrict__ bucket_base) {
    __shared__ int part[1024];
    int t = threadIdx.x;
    int v0 = (2 * t     < NBUCK) ? min(bucket_cnt[2 * t],     CAP) : 0;
    int v1 = (2 * t + 1 < NBUCK) ? min(bucket_cnt[2 * t + 1], CAP) : 0;
    part[t] = v0 + v1;
    __syncthreads();
    for (int off = 1; off < 1024; off <<= 1) {
        int u = (t >= off) ? part[t - off] : 0;
        __syncthreads();
        part[t] += u;
        __syncthreads();
    }
    int ex = (t == 0) ? 0 : part[t - 1];
    if (2 * t     < NBUCK) bucket_base[2 * t]     = ex;
    if (2 * t + 1 < NBUCK) bucket_base[2 * t + 1] = ex + v0;
}

// ---------------- phase 3: per-bucket histogram + scan + ordered scatter ----------------
// Produces rowptr, dinv, csr_src. One workgroup per bucket; csr_src writes are
// a private contiguous range per workgroup -> full-line writebacks.
__global__ __launch_bounds__(256) void build_kernel(const int* __restrict__ bucket_cnt,
                                                    const int* __restrict__ bucket_base,
                                                    const int* __restrict__ buf,
                                                    int* __restrict__ rowptr,
                                                    float* __restrict__ dinv,
                                                    int* __restrict__ csr_src) {
    __shared__ int edges[CAP];
    __shared__ int hist[64];
    __shared__ int offs[64];
    int b = blockIdx.x;
    int t = threadIdx.x;
    int cnt  = min(bucket_cnt[b], CAP);
    int base = bucket_base[b];

    for (int i = t; i < cnt; i += 256) edges[i] = buf[b * CAP + i];
    if (t < 64) hist[t] = 0;
    __syncthreads();
    for (int i = t; i < cnt; i += 256) atomicAdd(&hist[edges[i] >> 20], 1);
    __syncthreads();

    // exclusive scan of 64 counts in wave 0
    if (t < 64) {
        int v = hist[t];
        int inc = v;
        #pragma unroll
        for (int d = 1; d < 64; d <<= 1) {
            int u = __shfl_up(inc, d, 64);
            if (t >= d) inc += u;
        }
        offs[t] = inc - v;
    }
    __syncthreads();

    int n0 = b << BSHIFT;
    if (t < 64 && n0 + t < N_NODES) {
        rowptr[n0 + t] = base + offs[t];
        dinv[n0 + t]   = rsqrtf((float)(hist[t] + 1));  // +1 self-loop
    }
    if (b == 0 && t == 0) rowptr[N_NODES] = N_EDGES;
    __syncthreads();

    for (int i = t; i < cnt; i += 256) {
        int p = edges[i];
        int ld = p >> 20, src = p & 0xFFFFF;
        int pos = atomicAdd(&offs[ld], 1);
        csr_src[base + pos] = src;
    }
}

// ---------------- layer-1 GEMM: y1[n,h] = dinv[n] * sum_k x[n,k]*W1[k,h] ----------------
__global__ __launch_bounds__(256) void gemm1_kernel(const float* __restrict__ x,
                                                    const float* __restrict__ W1,
                                                    const float* __restrict__ dinv,
                                                    float* __restrict__ y1) {
    __shared__ float W1s[F_IN * HID];
    int t = threadIdx.x;
    #pragma unroll
    for (int i = 0; i < (F_IN * HID) / 256; i++) W1s[t + i * 256] = W1[t + i * 256];
    __syncthreads();

    int n = blockIdx.x * 256 + t;
    if (n >= N_NODES) return;

    const float4* xr = (const float4*)(x + (size_t)n * F_IN);
    float acc[HID];
    #pragma unroll
    for (int h = 0; h < HID; h++) acc[h] = 0.f;

    #pragma unroll 4
    for (int k4 = 0; k4 < F_IN / 4; k4++) {
        float4 xv = xr[k4];
        int k = k4 * 4;
        #pragma unroll
        for (int h = 0; h < HID; h++) {
            acc[h] += xv.x * W1s[(k + 0) * HID + h] + xv.y * W1s[(k + 1) * HID + h]
                    + xv.z * W1s[(k + 2) * HID + h] + xv.w * W1s[(k + 3) * HID + h];
        }
    }
    float dv = dinv[n];
    float4* o = (float4*)(y1 + (size_t)n * HID);
    #pragma unroll
    for (int q = 0; q < 4; q++)
        o[q] = make_float4(acc[4*q]*dv, acc[4*q+1]*dv, acc[4*q+2]*dv, acc[4*q+3]*dv);
}

// ---------------- gather 1: h1 = relu(dinv*(y1[n] + sum_src y1[src]) + b1) ----------------
__global__ void gather1_kernel(const int* __restrict__ rowptr, const int* __restrict__ csr_src,
                               const float* __restrict__ y1, const float* __restrict__ b1,
                               const float* __restrict__ dinv, float* __restrict__ h1) {
    int idx = blockIdx.x * blockDim.x + threadIdx.x;  // (node, quad)
    if (idx >= N_NODES * 4) return;
    int n = idx >> 2, q = idx & 3;
    int beg = rowptr[n], end = rowptr[n + 1];
    float4 acc = *(const float4*)(y1 + (size_t)n * HID + q * 4);  // self-loop
    int e = beg;
    for (; e + 1 < end; e += 2) {
        int s0 = csr_src[e], s1 = csr_src[e + 1];
        float4 v0 = *(const float4*)(y1 + (size_t)s0 * HID + q * 4);
        float4 v1 = *(const float4*)(y1 + (size_t)s1 * HID + q * 4);
        acc.x += v0.x + v1.x; acc.y += v0.y + v1.y;
        acc.z += v0.z + v1.z; acc.w += v0.w + v1.w;
    }
    if (e < end) {
        int s = csr_src[e];
        float4 v = *(const float4*)(y1 + (size_t)s * HID + q * 4);
        acc.x += v.x; acc.y += v.y; acc.z += v.z; acc.w += v.w;
    }
    float dv = dinv[n];
    float4 r;
    r.x = fmaxf(dv * acc.x + b1[q * 4 + 0], 0.f);
    r.y = fmaxf(dv * acc.y + b1[q * 4 + 1], 0.f);
    r.z = fmaxf(dv * acc.z + b1[q * 4 + 2], 0.f);
    r.w = fmaxf(dv * acc.w + b1[q * 4 + 3], 0.f);
    *(float4*)(h1 + (size_t)n * HID + q * 4) = r;
}

// ---------------- layer-2 GEMM: y2[n,c] = dinv[n] * sum_h h1[n,h]*W2[h,c] ----------------
__global__ __launch_bounds__(320) void gemm2_kernel(const float* __restrict__ h1,
                                                    const float* __restrict__ W2,
                                                    const float* __restrict__ dinv,
                                                    float* __restrict__ y2) {
    __shared__ float W2s[HID * NCLS];   // 640
    __shared__ float h1s[8 * HID];      // 128
    int t = threadIdx.x;
    for (int i = t; i < HID * NCLS; i += 320) W2s[i] = W2[i];
    int n0 = blockIdx.x * 8;
    if (t < 8 * HID) {
        int n = n0 + t / HID;
        h1s[t] = (n < N_NODES) ? h1[(size_t)n * HID + (t % HID)] : 0.f;
    }
    __syncthreads();
    int ln = t / NCLS, c = t % NCLS;
    int n = n0 + ln;
    if (ln >= 8 || n >= N_NODES) return;
    float s = 0.f;
    #pragma unroll
    for (int h = 0; h < HID; h++) s += h1s[ln * HID + h] * W2s[h * NCLS + c];
    y2[(size_t)n * NCLS + c] = dinv[n] * s;
}

// ---------------- gather 2: out = dinv*(y2[n] + sum_src y2[src]) + b2 ----------------
__global__ void gather2_kernel(const int* __restrict__ rowptr, const int* __restrict__ csr_src,
                               const float* __restrict__ y2, const float* __restrict__ b2,
                               const float* __restrict__ dinv, float* __restrict__ out) {
    int idx = blockIdx.x * blockDim.x + threadIdx.x;  // (node, tenth)
    if (idx >= N_NODES * 10) return;
    int n = idx / 10, q = idx - n * 10;
    int beg = rowptr[n], end = rowptr[n + 1];
    float4 acc = *(const float4*)(y2 + (size_t)n * NCLS + q * 4);  // self-loop
    int e = beg;
    for (; e + 1 < end; e += 2) {
        int s0 = csr_src[e], s1 = csr_src[e + 1];
        float4 v0 = *(const float4*)(y2 + (size_t)s0 * NCLS + q * 4);
        float4 v1 = *(const float4*)(y2 + (size_t)s1 * NCLS + q * 4);
        acc.x += v0.x + v1.x; acc.y += v0.y + v1.y;
        acc.z += v0.z + v1.z; acc.w += v0.w + v1.w;
    }
    if (e < end) {
        int s = csr_src[e];
        float4 v = *(const float4*)(y2 + (size_t)s * NCLS + q * 4);
        acc.x += v.x; acc.y += v.y; acc.z += v.z; acc.w += v.w;
    }
    float dv = dinv[n];
    float4 r;
    r.x = dv * acc.x + b2[q * 4 + 0];
    r.y = dv * acc.y + b2[q * 4 + 1];
    r.z = dv * acc.z + b2[q * 4 + 2];
    r.w = dv * acc.w + b2[q * 4 + 3];
    *(float4*)(out + (size_t)n * NCLS + q * 4) = r;
}

extern "C" void kernel_launch(void* const* d_in, const int* in_sizes, int n_in,
                              void* d_out, int out_size, void* d_ws, size_t ws_size,
                              hipStream_t stream) {
    const float* x   = (const float*)d_in[0];
    const int*   ei  = (const int*)  d_in[1];   // [2, E] int32
    const float* W1  = (const float*)d_in[2];
    const float* b1  = (const float*)d_in[3];
    const float* W2  = (const float*)d_in[4];
    const float* b2  = (const float*)d_in[5];
    float* out = (float*)d_out;

    char* ws = (char*)d_ws;
    size_t off = 0;
    int*   bucket_cnt  = (int*)(ws + off); off += (size_t)NBUCK * 4;
    int*   bucket_base = (int*)(ws + off); off += (size_t)NBUCK * 4;
    off = (off + 15) & ~(size_t)15;
    int*   rowptr  = (int*)  (ws + off); off += (size_t)(N_NODES + 1) * 4;
    off = (off + 15) & ~(size_t)15;
    float* dinv    = (float*)(ws + off); off += (size_t)N_NODES * 4;
    int*   csr_src = (int*)  (ws + off); off += (size_t)N_EDGES * 4;            // 12.8 MB
    float* y1      = (float*)(ws + off); off += (size_t)N_NODES * HID * 4;      //  6.4 MB
    float* h1      = (float*)(ws + off); off += (size_t)N_NODES * HID * 4;      //  6.4 MB
    // buf (16.0 MB) aliases y2 (16.0 MB): buf dead after build_kernel, y2 born in gemm2
    int*   buf     = (int*)  (ws + off);
    float* y2      = (float*)(ws + off); off += (size_t)NBUCK * CAP * 4;        // 16.0 MB

    hipMemsetAsync(bucket_cnt, 0, (size_t)NBUCK * 4, stream);

    bin_kernel  <<<(N_EDGES + 255) / 256, 256, 0, stream>>>(ei, bucket_cnt, buf);
    bscan_kernel<<<1, 1024, 0, stream>>>(bucket_cnt, bucket_base);
    build_kernel<<<NBUCK, 256, 0, stream>>>(bucket_cnt, bucket_base, buf, rowptr, dinv, csr_src);

    gemm1_kernel  <<<(N_NODES + 255) / 256, 256, 0, stream>>>(x, W1, dinv, y1);
    gather1_kernel<<<(N_NODES * 4 + 255) / 256, 256, 0, stream>>>(rowptr, csr_src, y1, b1, dinv, h1);
    gemm2_kernel  <<<(N_NODES + 7) / 8, 320, 0, stream>>>(h1, W2, dinv, y2);
    gather2_kernel<<<(N_NODES * 10 + 255) / 256, 256, 0, stream>>>(rowptr, csr_src, y2, b2, dinv, out);
}

// Round 5
// 490.164 us; speedup vs baseline: 1.7942x; 1.7942x over previous
//
#include <hip/hip_runtime.h>

#define N_NODES   100000
#define N_EDGES   3200000
#define F_IN      256
#define HID       16
#define NCLS      40

#define CHUNK     16384
#define NBLK      ((N_EDGES + CHUNK - 1) / CHUNK)    // 196 edge chunks
#define B2SHIFT   9                                  // 512 nodes per coarse bucket
#define NB2       ((N_NODES + 511) >> B2SHIFT)       // 196 buckets

// ---- phase A: per-chunk histogram over coarse dst buckets (LDS atomics only) ----
__global__ __launch_bounds__(256) void hist_kernel(const int* __restrict__ ei,
                                                   int* __restrict__ hist_blk) {
    __shared__ int h[NB2];
    int blk = blockIdx.x, t = threadIdx.x;
    for (int i = t; i < NB2; i += 256) h[i] = 0;
    __syncthreads();
    int e0 = blk * CHUNK;
    int eN = min(CHUNK, N_EDGES - e0);
    for (int i = t; i < eN; i += 256)
        atomicAdd(&h[ei[N_EDGES + e0 + i] >> B2SHIFT], 1);
    __syncthreads();
    for (int i = t; i < NB2; i += 256) hist_blk[i * NBLK + blk] = h[i];  // bucket-major
}

// ---- phase B1: exclusive scan within each bucket row (over blocks) ----
__global__ __launch_bounds__(256) void rowscan_kernel(int* __restrict__ hist_blk,
                                                      int* __restrict__ rowsum) {
    __shared__ int part[256];
    int b = blockIdx.x, t = threadIdx.x;
    int v = (t < NBLK) ? hist_blk[b * NBLK + t] : 0;
    part[t] = v;
    __syncthreads();
    for (int off = 1; off < 256; off <<= 1) {
        int u = (t >= off) ? part[t - off] : 0;
        __syncthreads();
        part[t] += u;
        __syncthreads();
    }
    if (t < NBLK) hist_blk[b * NBLK + t] = part[t] - v;  // exclusive within row
    if (t == 255) rowsum[b] = part[255];
}

// ---- phase B2: exclusive scan of bucket totals ----
__global__ __launch_bounds__(256) void basescan_kernel(const int* __restrict__ rowsum,
                                                       int* __restrict__ bucket_base) {
    __shared__ int part[256];
    int t = threadIdx.x;
    int v = (t < NB2) ? rowsum[t] : 0;
    part[t] = v;
    __syncthreads();
    for (int off = 1; off < 256; off <<= 1) {
        int u = (t >= off) ? part[t - off] : 0;
        __syncthreads();
        part[t] += u;
        __syncthreads();
    }
    if (t < NB2) bucket_base[t] = part[t] - v;
}

// ---- phase C: scatter edges into deterministic disjoint sub-ranges (no global atomics) ----
// pack: (dst & 511) << 17 | src   (src < 2^17)
__global__ __launch_bounds__(256) void bin2_kernel(const int* __restrict__ ei,
                                                   const int* __restrict__ hist_blk,
                                                   const int* __restrict__ bucket_base,
                                                   int* __restrict__ buf) {
    __shared__ int cur[NB2];
    int blk = blockIdx.x, t = threadIdx.x;
    for (int i = t; i < NB2; i += 256)
        cur[i] = bucket_base[i] + hist_blk[i * NBLK + blk];
    __syncthreads();
    int e0 = blk * CHUNK;
    int eN = min(CHUNK, N_EDGES - e0);
    for (int i = t; i < eN; i += 256) {
        int d = ei[N_EDGES + e0 + i];
        int s = ei[e0 + i];
        int pos = atomicAdd(&cur[d >> B2SHIFT], 1);   // LDS atomic
        buf[pos] = ((d & 511) << 17) | s;
    }
}

// ---- phase D: per-bucket fine build -> rowptr, dinv, csr_src ----
__global__ __launch_bounds__(512) void build_kernel(const int* __restrict__ buf,
                                                    const int* __restrict__ bucket_base,
                                                    const int* __restrict__ rowsum,
                                                    int* __restrict__ rowptr,
                                                    float* __restrict__ dinv,
                                                    int* __restrict__ csr_src) {
    __shared__ int hist[512], offs[512], cur[512];
    int b = blockIdx.x, t = threadIdx.x;
    int base = bucket_base[b];
    int cnt  = rowsum[b];
    hist[t] = 0;
    __syncthreads();
    for (int i = t; i < cnt; i += 512)
        atomicAdd(&hist[buf[base + i] >> 17], 1);
    __syncthreads();
    int v = hist[t];
    offs[t] = v;
    __syncthreads();
    for (int off = 1; off < 512; off <<= 1) {
        int u = (t >= off) ? offs[t - off] : 0;
        __syncthreads();
        offs[t] += u;
        __syncthreads();
    }
    int ex = offs[t] - v;   // exclusive scan
    int n = (b << B2SHIFT) + t;
    if (n < N_NODES) {
        rowptr[n] = base + ex;
        dinv[n]   = rsqrtf((float)(v + 1));  // +1 self-loop
    }
    if (b == 0 && t == 0) rowptr[N_NODES] = N_EDGES;
    cur[t] = ex;
    __syncthreads();
    for (int i = t; i < cnt; i += 512) {
        int p = buf[base + i];
        int pos = atomicAdd(&cur[p >> 17], 1);        // LDS atomic
        csr_src[base + pos] = p & 0x1FFFF;
    }
}

// ---------------- layer-1 GEMM: y1[n,h] = dinv[n] * sum_k x[n,k]*W1[k,h] ----------------
__global__ __launch_bounds__(256) void gemm1_kernel(const float* __restrict__ x,
                                                    const float* __restrict__ W1,
                                                    const float* __restrict__ dinv,
                                                    float* __restrict__ y1) {
    __shared__ float W1s[F_IN * HID];
    int t = threadIdx.x;
    #pragma unroll
    for (int i = 0; i < (F_IN * HID) / 256; i++) W1s[t + i * 256] = W1[t + i * 256];
    __syncthreads();

    int n = blockIdx.x * 256 + t;
    if (n >= N_NODES) return;

    const float4* xr = (const float4*)(x + (size_t)n * F_IN);
    float acc[HID];
    #pragma unroll
    for (int h = 0; h < HID; h++) acc[h] = 0.f;

    #pragma unroll 4
    for (int k4 = 0; k4 < F_IN / 4; k4++) {
        float4 xv = xr[k4];
        int k = k4 * 4;
        #pragma unroll
        for (int h = 0; h < HID; h++) {
            acc[h] += xv.x * W1s[(k + 0) * HID + h] + xv.y * W1s[(k + 1) * HID + h]
                    + xv.z * W1s[(k + 2) * HID + h] + xv.w * W1s[(k + 3) * HID + h];
        }
    }
    float dv = dinv[n];
    float4* o = (float4*)(y1 + (size_t)n * HID);
    #pragma unroll
    for (int q = 0; q < 4; q++)
        o[q] = make_float4(acc[4*q]*dv, acc[4*q+1]*dv, acc[4*q+2]*dv, acc[4*q+3]*dv);
}

// ---------------- gather 1: h1 = relu(dinv*(y1[n] + sum_src y1[src]) + b1) ----------------
__global__ void gather1_kernel(const int* __restrict__ rowptr, const int* __restrict__ csr_src,
                               const float* __restrict__ y1, const float* __restrict__ b1,
                               const float* __restrict__ dinv, float* __restrict__ h1) {
    int idx = blockIdx.x * blockDim.x + threadIdx.x;  // (node, quad)
    if (idx >= N_NODES * 4) return;
    int n = idx >> 2, q = idx & 3;
    int beg = rowptr[n], end = rowptr[n + 1];
    float4 acc = *(const float4*)(y1 + (size_t)n * HID + q * 4);  // self-loop
    int e = beg;
    for (; e + 1 < end; e += 2) {
        int s0 = csr_src[e], s1 = csr_src[e + 1];
        float4 v0 = *(const float4*)(y1 + (size_t)s0 * HID + q * 4);
        float4 v1 = *(const float4*)(y1 + (size_t)s1 * HID + q * 4);
        acc.x += v0.x + v1.x; acc.y += v0.y + v1.y;
        acc.z += v0.z + v1.z; acc.w += v0.w + v1.w;
    }
    if (e < end) {
        int s = csr_src[e];
        float4 v = *(const float4*)(y1 + (size_t)s * HID + q * 4);
        acc.x += v.x; acc.y += v.y; acc.z += v.z; acc.w += v.w;
    }
    float dv = dinv[n];
    float4 r;
    r.x = fmaxf(dv * acc.x + b1[q * 4 + 0], 0.f);
    r.y = fmaxf(dv * acc.y + b1[q * 4 + 1], 0.f);
    r.z = fmaxf(dv * acc.z + b1[q * 4 + 2], 0.f);
    r.w = fmaxf(dv * acc.w + b1[q * 4 + 3], 0.f);
    *(float4*)(h1 + (size_t)n * HID + q * 4) = r;
}

// ---------------- layer-2 GEMM: y2[n,c] = dinv[n] * sum_h h1[n,h]*W2[h,c] ----------------
__global__ __launch_bounds__(320) void gemm2_kernel(const float* __restrict__ h1,
                                                    const float* __restrict__ W2,
                                                    const float* __restrict__ dinv,
                                                    float* __restrict__ y2) {
    __shared__ float W2s[HID * NCLS];   // 640
    __shared__ float h1s[8 * HID];      // 128
    int t = threadIdx.x;
    for (int i = t; i < HID * NCLS; i += 320) W2s[i] = W2[i];
    int n0 = blockIdx.x * 8;
    if (t < 8 * HID) {
        int n = n0 + t / HID;
        h1s[t] = (n < N_NODES) ? h1[(size_t)n * HID + (t % HID)] : 0.f;
    }
    __syncthreads();
    int ln = t / NCLS, c = t % NCLS;
    int n = n0 + ln;
    if (ln >= 8 || n >= N_NODES) return;
    float s = 0.f;
    #pragma unroll
    for (int h = 0; h < HID; h++) s += h1s[ln * HID + h] * W2s[h * NCLS + c];
    y2[(size_t)n * NCLS + c] = dinv[n] * s;
}

// ---------------- gather 2: out = dinv*(y2[n] + sum_src y2[src]) + b2 ----------------
__global__ void gather2_kernel(const int* __restrict__ rowptr, const int* __restrict__ csr_src,
                               const float* __restrict__ y2, const float* __restrict__ b2,
                               const float* __restrict__ dinv, float* __restrict__ out) {
    int idx = blockIdx.x * blockDim.x + threadIdx.x;  // (node, tenth)
    if (idx >= N_NODES * 10) return;
    int n = idx / 10, q = idx - n * 10;
    int beg = rowptr[n], end = rowptr[n + 1];
    float4 acc = *(const float4*)(y2 + (size_t)n * NCLS + q * 4);  // self-loop
    int e = beg;
    for (; e + 1 < end; e += 2) {
        int s0 = csr_src[e], s1 = csr_src[e + 1];
        float4 v0 = *(const float4*)(y2 + (size_t)s0 * NCLS + q * 4);
        float4 v1 = *(const float4*)(y2 + (size_t)s1 * NCLS + q * 4);
        acc.x += v0.x + v1.x; acc.y += v0.y + v1.y;
        acc.z += v0.z + v1.z; acc.w += v0.w + v1.w;
    }
    if (e < end) {
        int s = csr_src[e];
        float4 v = *(const float4*)(y2 + (size_t)s * NCLS + q * 4);
        acc.x += v.x; acc.y += v.y; acc.z += v.z; acc.w += v.w;
    }
    float dv = dinv[n];
    float4 r;
    r.x = dv * acc.x + b2[q * 4 + 0];
    r.y = dv * acc.y + b2[q * 4 + 1];
    r.z = dv * acc.z + b2[q * 4 + 2];
    r.w = dv * acc.w + b2[q * 4 + 3];
    *(float4*)(out + (size_t)n * NCLS + q * 4) = r;
}

extern "C" void kernel_launch(void* const* d_in, const int* in_sizes, int n_in,
                              void* d_out, int out_size, void* d_ws, size_t ws_size,
                              hipStream_t stream) {
    const float* x   = (const float*)d_in[0];
    const int*   ei  = (const int*)  d_in[1];   // [2, E] int32
    const float* W1  = (const float*)d_in[2];
    const float* b1  = (const float*)d_in[3];
    const float* W2  = (const float*)d_in[4];
    const float* b2  = (const float*)d_in[5];
    float* out = (float*)d_out;

    char* ws = (char*)d_ws;
    size_t off = 0;
    int*   hist_blk    = (int*)(ws + off); off += (size_t)NB2 * NBLK * 4;       // 154 KB
    int*   rowsum      = (int*)(ws + off); off += (size_t)NB2 * 4;
    int*   bucket_base = (int*)(ws + off); off += (size_t)NB2 * 4;
    off = (off + 15) & ~(size_t)15;
    int*   rowptr  = (int*)  (ws + off); off += (size_t)(N_NODES + 1) * 4;
    off = (off + 15) & ~(size_t)15;
    float* dinv    = (float*)(ws + off); off += (size_t)N_NODES * 4;
    int*   csr_src = (int*)  (ws + off); off += (size_t)N_EDGES * 4;            // 12.8 MB
    float* y1      = (float*)(ws + off); off += (size_t)N_NODES * HID * 4;      //  6.4 MB
    float* h1      = (float*)(ws + off); off += (size_t)N_NODES * HID * 4;      //  6.4 MB
    // buf (12.8 MB) aliases y2 (16 MB): buf dead after build_kernel, y2 born in gemm2
    int*   buf     = (int*)  (ws + off);
    float* y2      = (float*)(ws + off); off += (size_t)N_NODES * NCLS * 4;     // 16.0 MB

    hist_kernel    <<<NBLK, 256, 0, stream>>>(ei, hist_blk);
    rowscan_kernel <<<NB2, 256, 0, stream>>>(hist_blk, rowsum);
    basescan_kernel<<<1, 256, 0, stream>>>(rowsum, bucket_base);
    bin2_kernel    <<<NBLK, 256, 0, stream>>>(ei, hist_blk, bucket_base, buf);
    build_kernel   <<<NB2, 512, 0, stream>>>(buf, bucket_base, rowsum, rowptr, dinv, csr_src);

    gemm1_kernel  <<<(N_NODES + 255) / 256, 256, 0, stream>>>(x, W1, dinv, y1);
    gather1_kernel<<<(N_NODES * 4 + 255) / 256, 256, 0, stream>>>(rowptr, csr_src, y1, b1, dinv, h1);
    gemm2_kernel  <<<(N_NODES + 7) / 8, 320, 0, stream>>>(h1, W2, dinv, y2);
    gather2_kernel<<<(N_NODES * 10 + 255) / 256, 256, 0, stream>>>(rowptr, csr_src, y2, b2, dinv, out);
}

// Round 6
// 389.898 us; speedup vs baseline: 2.2555x; 1.2572x over previous
//
#include <hip/hip_runtime.h>
#include <hip/hip_fp16.h>

#define N_NODES   100000
#define N_EDGES   3200000
#define F_IN      256
#define HID       16
#define NCLS      40

#define CHUNK     16384
#define NBLK      ((N_EDGES + CHUNK - 1) / CHUNK)    // 196 edge chunks
#define B2SHIFT   9                                  // 512 nodes per coarse bucket
#define NB2       ((N_NODES + 511) >> B2SHIFT)       // 196 buckets

// ---- phase A: per-chunk histogram over coarse dst buckets (LDS atomics only) ----
__global__ __launch_bounds__(256) void hist_kernel(const int* __restrict__ ei,
                                                   int* __restrict__ hist_blk) {
    __shared__ int h[NB2];
    int blk = blockIdx.x, t = threadIdx.x;
    for (int i = t; i < NB2; i += 256) h[i] = 0;
    __syncthreads();
    int e0 = blk * CHUNK;
    int eN = min(CHUNK, N_EDGES - e0);
    for (int i = t; i < eN; i += 256)
        atomicAdd(&h[ei[N_EDGES + e0 + i] >> B2SHIFT], 1);
    __syncthreads();
    for (int i = t; i < NB2; i += 256) hist_blk[i * NBLK + blk] = h[i];  // bucket-major
}

// ---- phase B1: exclusive scan within each bucket row (over blocks) ----
__global__ __launch_bounds__(256) void rowscan_kernel(int* __restrict__ hist_blk,
                                                      int* __restrict__ rowsum) {
    __shared__ int part[256];
    int b = blockIdx.x, t = threadIdx.x;
    int v = (t < NBLK) ? hist_blk[b * NBLK + t] : 0;
    part[t] = v;
    __syncthreads();
    for (int off = 1; off < 256; off <<= 1) {
        int u = (t >= off) ? part[t - off] : 0;
        __syncthreads();
        part[t] += u;
        __syncthreads();
    }
    if (t < NBLK) hist_blk[b * NBLK + t] = part[t] - v;  // exclusive within row
    if (t == 255) rowsum[b] = part[255];
}

// ---- phase B2: exclusive scan of bucket totals ----
__global__ __launch_bounds__(256) void basescan_kernel(const int* __restrict__ rowsum,
                                                       int* __restrict__ bucket_base) {
    __shared__ int part[256];
    int t = threadIdx.x;
    int v = (t < NB2) ? rowsum[t] : 0;
    part[t] = v;
    __syncthreads();
    for (int off = 1; off < 256; off <<= 1) {
        int u = (t >= off) ? part[t - off] : 0;
        __syncthreads();
        part[t] += u;
        __syncthreads();
    }
    if (t < NB2) bucket_base[t] = part[t] - v;
}

// ---- phase C: scatter edges into deterministic disjoint sub-ranges (no global atomics) ----
// pack: (dst & 511) << 17 | src   (src < 2^17)
__global__ __launch_bounds__(256) void bin2_kernel(const int* __restrict__ ei,
                                                   const int* __restrict__ hist_blk,
                                                   const int* __restrict__ bucket_base,
                                                   int* __restrict__ buf) {
    __shared__ int cur[NB2];
    int blk = blockIdx.x, t = threadIdx.x;
    for (int i = t; i < NB2; i += 256)
        cur[i] = bucket_base[i] + hist_blk[i * NBLK + blk];
    __syncthreads();
    int e0 = blk * CHUNK;
    int eN = min(CHUNK, N_EDGES - e0);
    for (int i = t; i < eN; i += 256) {
        int d = ei[N_EDGES + e0 + i];
        int s = ei[e0 + i];
        int pos = atomicAdd(&cur[d >> B2SHIFT], 1);   // LDS atomic
        buf[pos] = ((d & 511) << 17) | s;
    }
}

// ---- phase D: per-bucket fine build -> rowptr, dinv, csr_src ----
__global__ __launch_bounds__(512) void build_kernel(const int* __restrict__ buf,
                                                    const int* __restrict__ bucket_base,
                                                    const int* __restrict__ rowsum,
                                                    int* __restrict__ rowptr,
                                                    float* __restrict__ dinv,
                                                    int* __restrict__ csr_src) {
    __shared__ int hist[512], offs[512], cur[512];
    int b = blockIdx.x, t = threadIdx.x;
    int base = bucket_base[b];
    int cnt  = rowsum[b];
    hist[t] = 0;
    __syncthreads();
    for (int i = t; i < cnt; i += 512)
        atomicAdd(&hist[buf[base + i] >> 17], 1);
    __syncthreads();
    int v = hist[t];
    offs[t] = v;
    __syncthreads();
    for (int off = 1; off < 512; off <<= 1) {
        int u = (t >= off) ? offs[t - off] : 0;
        __syncthreads();
        offs[t] += u;
        __syncthreads();
    }
    int ex = offs[t] - v;   // exclusive scan
    int n = (b << B2SHIFT) + t;
    if (n < N_NODES) {
        rowptr[n] = base + ex;
        dinv[n]   = rsqrtf((float)(v + 1));  // +1 self-loop
    }
    if (b == 0 && t == 0) rowptr[N_NODES] = N_EDGES;
    cur[t] = ex;
    __syncthreads();
    for (int i = t; i < cnt; i += 512) {
        int p = buf[base + i];
        int pos = atomicAdd(&cur[p >> 17], 1);        // LDS atomic
        csr_src[base + pos] = p & 0x1FFFF;
    }
}

// ---------------- layer-1 GEMM: y1h[n,h] = fp16( dinv[n] * sum_k x[n,k]*W1[k,h] ) ----------------
__global__ __launch_bounds__(256) void gemm1_kernel(const float* __restrict__ x,
                                                    const float* __restrict__ W1,
                                                    const float* __restrict__ dinv,
                                                    __half* __restrict__ y1h) {
    __shared__ float W1s[F_IN * HID];
    int t = threadIdx.x;
    #pragma unroll
    for (int i = 0; i < (F_IN * HID) / 256; i++) W1s[t + i * 256] = W1[t + i * 256];
    __syncthreads();

    int n = blockIdx.x * 256 + t;
    if (n >= N_NODES) return;

    const float4* xr = (const float4*)(x + (size_t)n * F_IN);
    float acc[HID];
    #pragma unroll
    for (int h = 0; h < HID; h++) acc[h] = 0.f;

    #pragma unroll 4
    for (int k4 = 0; k4 < F_IN / 4; k4++) {
        float4 xv = xr[k4];
        int k = k4 * 4;
        #pragma unroll
        for (int h = 0; h < HID; h++) {
            acc[h] += xv.x * W1s[(k + 0) * HID + h] + xv.y * W1s[(k + 1) * HID + h]
                    + xv.z * W1s[(k + 2) * HID + h] + xv.w * W1s[(k + 3) * HID + h];
        }
    }
    float dv = dinv[n];
    __half2 hp[8];
    #pragma unroll
    for (int j = 0; j < 8; j++)
        hp[j] = __float22half2_rn(make_float2(acc[2 * j] * dv, acc[2 * j + 1] * dv));
    float4* o = (float4*)(y1h + (size_t)n * HID);
    o[0] = ((float4*)hp)[0];
    o[1] = ((float4*)hp)[1];
}

// ---------------- gather 1: zh = fp16( dinv * relu(dinv*(y1[n] + sum_src y1[src]) + b1) ) ----------------
__global__ void gather1_kernel(const int* __restrict__ rowptr, const int* __restrict__ csr_src,
                               const __half* __restrict__ y1h, const float* __restrict__ b1,
                               const float* __restrict__ dinv, __half* __restrict__ zh) {
    int idx = blockIdx.x * blockDim.x + threadIdx.x;  // (node, half-row)
    if (idx >= N_NODES * 2) return;
    int n = idx >> 1, q = idx & 1;
    int beg = rowptr[n], end = rowptr[n + 1];
    const float4* tab = (const float4*)y1h;           // one float4 = 8 halfs; row = 2 float4
    float acc[8];
    {
        float4 v = tab[(size_t)n * 2 + q];            // self-loop
        const __half2* a = (const __half2*)&v;
        #pragma unroll
        for (int j = 0; j < 4; j++) {
            float2 f = __half22float2(a[j]);
            acc[2 * j] = f.x; acc[2 * j + 1] = f.y;
        }
    }
    int e = beg;
    for (; e + 1 < end; e += 2) {
        int s0 = csr_src[e], s1 = csr_src[e + 1];
        float4 v0 = tab[(size_t)s0 * 2 + q];
        float4 v1 = tab[(size_t)s1 * 2 + q];
        const __half2* a0 = (const __half2*)&v0;
        const __half2* a1 = (const __half2*)&v1;
        #pragma unroll
        for (int j = 0; j < 4; j++) {
            float2 f0 = __half22float2(a0[j]);
            float2 f1 = __half22float2(a1[j]);
            acc[2 * j]     += f0.x + f1.x;
            acc[2 * j + 1] += f0.y + f1.y;
        }
    }
    if (e < end) {
        int s = csr_src[e];
        float4 v = tab[(size_t)s * 2 + q];
        const __half2* a = (const __half2*)&v;
        #pragma unroll
        for (int j = 0; j < 4; j++) {
            float2 f = __half22float2(a[j]);
            acc[2 * j] += f.x; acc[2 * j + 1] += f.y;
        }
    }
    float dv = dinv[n];
    __half2 outp[4];
    #pragma unroll
    for (int j = 0; j < 4; j++) {
        float2 r;
        r.x = fmaxf(dv * acc[2 * j]     + b1[q * 8 + 2 * j],     0.f) * dv;
        r.y = fmaxf(dv * acc[2 * j + 1] + b1[q * 8 + 2 * j + 1], 0.f) * dv;
        outp[j] = __float22half2_rn(r);
    }
    *(float4*)(zh + (size_t)n * HID + q * 8) = *(float4*)outp;
}

// ---------------- gather 2: agg2[n] = z[n] + sum_src z[src]  (fp32 out) ----------------
__global__ void gather2_kernel(const int* __restrict__ rowptr, const int* __restrict__ csr_src,
                               const __half* __restrict__ zh, float* __restrict__ agg2) {
    int idx = blockIdx.x * blockDim.x + threadIdx.x;  // (node, half-row)
    if (idx >= N_NODES * 2) return;
    int n = idx >> 1, q = idx & 1;
    int beg = rowptr[n], end = rowptr[n + 1];
    const float4* tab = (const float4*)zh;
    float acc[8];
    {
        float4 v = tab[(size_t)n * 2 + q];            // self-loop
        const __half2* a = (const __half2*)&v;
        #pragma unroll
        for (int j = 0; j < 4; j++) {
            float2 f = __half22float2(a[j]);
            acc[2 * j] = f.x; acc[2 * j + 1] = f.y;
        }
    }
    int e = beg;
    for (; e + 1 < end; e += 2) {
        int s0 = csr_src[e], s1 = csr_src[e + 1];
        float4 v0 = tab[(size_t)s0 * 2 + q];
        float4 v1 = tab[(size_t)s1 * 2 + q];
        const __half2* a0 = (const __half2*)&v0;
        const __half2* a1 = (const __half2*)&v1;
        #pragma unroll
        for (int j = 0; j < 4; j++) {
            float2 f0 = __half22float2(a0[j]);
            float2 f1 = __half22float2(a1[j]);
            acc[2 * j]     += f0.x + f1.x;
            acc[2 * j + 1] += f0.y + f1.y;
        }
    }
    if (e < end) {
        int s = csr_src[e];
        float4 v = tab[(size_t)s * 2 + q];
        const __half2* a = (const __half2*)&v;
        #pragma unroll
        for (int j = 0; j < 4; j++) {
            float2 f = __half22float2(a[j]);
            acc[2 * j] += f.x; acc[2 * j + 1] += f.y;
        }
    }
    float4* o = (float4*)(agg2 + (size_t)n * HID + q * 8);
    o[0] = make_float4(acc[0], acc[1], acc[2], acc[3]);
    o[1] = make_float4(acc[4], acc[5], acc[6], acc[7]);
}

// ---------------- output GEMM: out[n,c] = dinv[n]*(agg2[n,:]@W2[:,c]) + b2[c] ----------------
__global__ __launch_bounds__(320) void gemm2_kernel(const float* __restrict__ agg2,
                                                    const float* __restrict__ W2,
                                                    const float* __restrict__ dinv,
                                                    const float* __restrict__ b2,
                                                    float* __restrict__ out) {
    __shared__ float W2s[HID * NCLS];   // 640
    __shared__ float hs[8 * HID];       // 128
    __shared__ float b2s[NCLS];
    int t = threadIdx.x;
    for (int i = t; i < HID * NCLS; i += 320) W2s[i] = W2[i];
    if (t < NCLS) b2s[t] = b2[t];
    int n0 = blockIdx.x * 8;
    if (t < 8 * HID) {
        int n = n0 + t / HID;
        hs[t] = (n < N_NODES) ? agg2[(size_t)n * HID + (t % HID)] : 0.f;
    }
    __syncthreads();
    int ln = t / NCLS, c = t % NCLS;
    int n = n0 + ln;
    if (ln >= 8 || n >= N_NODES) return;
    float s = 0.f;
    #pragma unroll
    for (int h = 0; h < HID; h++) s += hs[ln * HID + h] * W2s[h * NCLS + c];
    out[(size_t)n * NCLS + c] = dinv[n] * s + b2s[c];
}

extern "C" void kernel_launch(void* const* d_in, const int* in_sizes, int n_in,
                              void* d_out, int out_size, void* d_ws, size_t ws_size,
                              hipStream_t stream) {
    const float* x   = (const float*)d_in[0];
    const int*   ei  = (const int*)  d_in[1];   // [2, E] int32
    const float* W1  = (const float*)d_in[2];
    const float* b1  = (const float*)d_in[3];
    const float* W2  = (const float*)d_in[4];
    const float* b2  = (const float*)d_in[5];
    float* out = (float*)d_out;

    char* ws = (char*)d_ws;
    size_t off = 0;
    int*   hist_blk    = (int*)(ws + off); off += (size_t)NB2 * NBLK * 4;       // 154 KB
    int*   rowsum      = (int*)(ws + off); off += (size_t)NB2 * 4;
    int*   bucket_base = (int*)(ws + off); off += (size_t)NB2 * 4;
    off = (off + 15) & ~(size_t)15;
    int*    rowptr  = (int*)   (ws + off); off += (size_t)(N_NODES + 1) * 4;
    off = (off + 15) & ~(size_t)15;
    float*  dinv    = (float*) (ws + off); off += (size_t)N_NODES * 4;
    int*    csr_src = (int*)   (ws + off); off += (size_t)N_EDGES * 4;          // 12.8 MB
    int*    buf     = (int*)   (ws + off); off += (size_t)N_EDGES * 4;          // 12.8 MB
    __half* y1h     = (__half*)(ws + off); off += (size_t)N_NODES * HID * 2;    //  3.2 MB
    __half* zh      = (__half*)(ws + off); off += (size_t)N_NODES * HID * 2;    //  3.2 MB
    float*  agg2    = (float*) (ws + off); off += (size_t)N_NODES * HID * 4;    //  6.4 MB

    hist_kernel    <<<NBLK, 256, 0, stream>>>(ei, hist_blk);
    rowscan_kernel <<<NB2, 256, 0, stream>>>(hist_blk, rowsum);
    basescan_kernel<<<1, 256, 0, stream>>>(rowsum, bucket_base);
    bin2_kernel    <<<NBLK, 256, 0, stream>>>(ei, hist_blk, bucket_base, buf);
    build_kernel   <<<NB2, 512, 0, stream>>>(buf, bucket_base, rowsum, rowptr, dinv, csr_src);

    gemm1_kernel  <<<(N_NODES + 255) / 256, 256, 0, stream>>>(x, W1, dinv, y1h);
    gather1_kernel<<<(N_NODES * 2 + 255) / 256, 256, 0, stream>>>(rowptr, csr_src, y1h, b1, dinv, zh);
    gather2_kernel<<<(N_NODES * 2 + 255) / 256, 256, 0, stream>>>(rowptr, csr_src, zh, agg2);
    gemm2_kernel  <<<(N_NODES + 7) / 8, 320, 0, stream>>>(agg2, W2, dinv, b2, out);
}

// Round 7
// 357.883 us; speedup vs baseline: 2.4573x; 1.0895x over previous
//
#include <hip/hip_runtime.h>
#include <hip/hip_fp16.h>

#define N_NODES   100000
#define N_EDGES   3200000
#define F_IN      256
#define HID       16
#define NCLS      40

#define CHUNK     16384
#define NBLK      ((N_EDGES + CHUNK - 1) / CHUNK)    // 196 edge chunks
#define B2SHIFT   9                                  // 512 nodes per coarse bucket
#define NB2       ((N_NODES + 511) >> B2SHIFT)       // 196 buckets
#define BCAP      17408                              // LDS edge cache in build (mean 16384, +8 sigma)

// ---- phase A: per-chunk histogram over coarse dst buckets (LDS atomics only) ----
__global__ __launch_bounds__(256) void hist_kernel(const int* __restrict__ ei,
                                                   int* __restrict__ hist_blk) {
    __shared__ int h[NB2];
    int blk = blockIdx.x, t = threadIdx.x;
    for (int i = t; i < NB2; i += 256) h[i] = 0;
    __syncthreads();
    int e0 = blk * CHUNK;
    int eN = min(CHUNK, N_EDGES - e0);
    for (int i = t; i < eN; i += 256)
        atomicAdd(&h[ei[N_EDGES + e0 + i] >> B2SHIFT], 1);
    __syncthreads();
    for (int i = t; i < NB2; i += 256) hist_blk[i * NBLK + blk] = h[i];  // bucket-major
}

// ---- phase B1: exclusive scan within each bucket row (over blocks) ----
__global__ __launch_bounds__(256) void rowscan_kernel(int* __restrict__ hist_blk,
                                                      int* __restrict__ rowsum) {
    __shared__ int part[256];
    int b = blockIdx.x, t = threadIdx.x;
    int v = (t < NBLK) ? hist_blk[b * NBLK + t] : 0;
    part[t] = v;
    __syncthreads();
    for (int off = 1; off < 256; off <<= 1) {
        int u = (t >= off) ? part[t - off] : 0;
        __syncthreads();
        part[t] += u;
        __syncthreads();
    }
    if (t < NBLK) hist_blk[b * NBLK + t] = part[t] - v;  // exclusive within row
    if (t == 255) rowsum[b] = part[255];
}

// ---- phase B2: exclusive scan of bucket totals ----
__global__ __launch_bounds__(256) void basescan_kernel(const int* __restrict__ rowsum,
                                                       int* __restrict__ bucket_base) {
    __shared__ int part[256];
    int t = threadIdx.x;
    int v = (t < NB2) ? rowsum[t] : 0;
    part[t] = v;
    __syncthreads();
    for (int off = 1; off < 256; off <<= 1) {
        int u = (t >= off) ? part[t - off] : 0;
        __syncthreads();
        part[t] += u;
        __syncthreads();
    }
    if (t < NB2) bucket_base[t] = part[t] - v;
}

// ---- phase C: scatter edges into deterministic disjoint sub-ranges (no global atomics) ----
// pack: (dst & 511) << 17 | src   (src < 2^17)
__global__ __launch_bounds__(256) void bin2_kernel(const int* __restrict__ ei,
                                                   const int* __restrict__ hist_blk,
                                                   const int* __restrict__ bucket_base,
                                                   int* __restrict__ buf) {
    __shared__ int cur[NB2];
    int blk = blockIdx.x, t = threadIdx.x;
    for (int i = t; i < NB2; i += 256)
        cur[i] = bucket_base[i] + hist_blk[i * NBLK + blk];
    __syncthreads();
    int e0 = blk * CHUNK;
    int eN = min(CHUNK, N_EDGES - e0);
    for (int i = t; i < eN; i += 256) {
        int d = ei[N_EDGES + e0 + i];
        int s = ei[e0 + i];
        int pos = atomicAdd(&cur[d >> B2SHIFT], 1);   // LDS atomic
        buf[pos] = ((d & 511) << 17) | s;
    }
}

// ---- phase D: per-bucket fine build -> rowptr, dinv, csr_src (bucket cached in LDS) ----
__global__ __launch_bounds__(512) void build_kernel(const int* __restrict__ buf,
                                                    const int* __restrict__ bucket_base,
                                                    const int* __restrict__ rowsum,
                                                    int* __restrict__ rowptr,
                                                    float* __restrict__ dinv,
                                                    int* __restrict__ csr_src) {
    __shared__ int lbuf[BCAP];
    __shared__ int hist[512], offs[512], cur[512];
    int b = blockIdx.x, t = threadIdx.x;
    int base = bucket_base[b];
    int cnt  = rowsum[b];
    hist[t] = 0;
    __syncthreads();
    for (int i = t; i < cnt; i += 512) {
        int v = buf[base + i];
        if (i < BCAP) lbuf[i] = v;
        atomicAdd(&hist[v >> 17], 1);
    }
    __syncthreads();
    int v = hist[t];
    offs[t] = v;
    __syncthreads();
    for (int off = 1; off < 512; off <<= 1) {
        int u = (t >= off) ? offs[t - off] : 0;
        __syncthreads();
        offs[t] += u;
        __syncthreads();
    }
    int ex = offs[t] - v;   // exclusive scan
    int n = (b << B2SHIFT) + t;
    if (n < N_NODES) {
        rowptr[n] = base + ex;
        dinv[n]   = rsqrtf((float)(v + 1));  // +1 self-loop
    }
    if (b == 0 && t == 0) rowptr[N_NODES] = N_EDGES;
    cur[t] = ex;
    __syncthreads();
    for (int i = t; i < cnt; i += 512) {
        int p = (i < BCAP) ? lbuf[i] : buf[base + i];
        int pos = atomicAdd(&cur[p >> 17], 1);        // LDS atomic
        csr_src[base + pos] = p & 0x1FFFF;
    }
}

// ---------------- layer-1 GEMM: y1h[n,h] = fp16( dinv[n] * sum_k x[n,k]*W1[k,h] ) ----------------
__global__ __launch_bounds__(256) void gemm1_kernel(const float* __restrict__ x,
                                                    const float* __restrict__ W1,
                                                    const float* __restrict__ dinv,
                                                    __half* __restrict__ y1h) {
    __shared__ float W1s[F_IN * HID];
    int t = threadIdx.x;
    #pragma unroll
    for (int i = 0; i < (F_IN * HID) / 256; i++) W1s[t + i * 256] = W1[t + i * 256];
    __syncthreads();

    int n = blockIdx.x * 256 + t;
    if (n >= N_NODES) return;

    const float4* xr = (const float4*)(x + (size_t)n * F_IN);
    float acc[HID];
    #pragma unroll
    for (int h = 0; h < HID; h++) acc[h] = 0.f;

    #pragma unroll 4
    for (int k4 = 0; k4 < F_IN / 4; k4++) {
        float4 xv = xr[k4];
        int k = k4 * 4;
        #pragma unroll
        for (int h = 0; h < HID; h++) {
            acc[h] += xv.x * W1s[(k + 0) * HID + h] + xv.y * W1s[(k + 1) * HID + h]
                    + xv.z * W1s[(k + 2) * HID + h] + xv.w * W1s[(k + 3) * HID + h];
        }
    }
    float dv = dinv[n];
    __half2 hp[8];
    #pragma unroll
    for (int j = 0; j < 8; j++)
        hp[j] = __float22half2_rn(make_float2(acc[2 * j] * dv, acc[2 * j + 1] * dv));
    float4* o = (float4*)(y1h + (size_t)n * HID);
    o[0] = ((float4*)hp)[0];
    o[1] = ((float4*)hp)[1];
}

// ---- helper: accumulate one fp16 row (16 halfs as 2 float4) into acc[16] ----
__device__ __forceinline__ void acc_row(const float4* __restrict__ tab, int s, float* acc) {
    float4 v0 = tab[(size_t)s * 2 + 0];
    float4 v1 = tab[(size_t)s * 2 + 1];
    const __half2* a0 = (const __half2*)&v0;
    const __half2* a1 = (const __half2*)&v1;
    #pragma unroll
    for (int j = 0; j < 4; j++) {
        float2 f0 = __half22float2(a0[j]);
        float2 f1 = __half22float2(a1[j]);
        acc[2 * j]         += f0.x;
        acc[2 * j + 1]     += f0.y;
        acc[8 + 2 * j]     += f1.x;
        acc[8 + 2 * j + 1] += f1.y;
    }
}

// ---------------- gather 1 (wave-coop, 16 lanes/node): zh = fp16(dinv*relu(dinv*agg + b1)) ----------------
__global__ __launch_bounds__(256) void gather1_kernel(const int* __restrict__ rowptr,
                                                      const int* __restrict__ csr_src,
                                                      const __half* __restrict__ y1h,
                                                      const float* __restrict__ b1,
                                                      const float* __restrict__ dinv,
                                                      __half* __restrict__ zh) {
    int n   = blockIdx.x * 16 + (threadIdx.x >> 4);
    int sub = threadIdx.x & 15;
    const float4* tab = (const float4*)y1h;
    int beg = rowptr[n], end = rowptr[n + 1];
    float acc[16];
    #pragma unroll
    for (int i = 0; i < 16; i++) acc[i] = 0.f;
    if (sub == 0) acc_row(tab, n, acc);               // self-loop
    for (int e = beg + sub; e < end; e += 16)
        acc_row(tab, csr_src[e], acc);
    // butterfly reduce across the 16-lane group
    #pragma unroll
    for (int m = 1; m < 16; m <<= 1) {
        #pragma unroll
        for (int i = 0; i < 16; i++) acc[i] += __shfl_xor(acc[i], m, 16);
    }
    if (sub < 2) {
        float dv = dinv[n];
        const float4* b1q = (const float4*)b1;
        float4 ba = b1q[sub * 2], bb = b1q[sub * 2 + 1];
        const float* bp = (sub == 0) ? (const float*)&ba : (const float*)&ba; // per-lane
        float bv[8] = {ba.x, ba.y, ba.z, ba.w, bb.x, bb.y, bb.z, bb.w};
        (void)bp;
        __half2 outp[4];
        #pragma unroll
        for (int j = 0; j < 4; j++) {
            float2 r;
            r.x = fmaxf(dv * acc[sub * 8 + 2 * j]     + bv[2 * j],     0.f) * dv;
            r.y = fmaxf(dv * acc[sub * 8 + 2 * j + 1] + bv[2 * j + 1], 0.f) * dv;
            outp[j] = __float22half2_rn(r);
        }
        *(float4*)(zh + (size_t)n * HID + sub * 8) = *(float4*)outp;
    }
}

// ---------------- gather 2 + output GEMM fused: out[n,c] = dinv*(agg@W2)[c] + b2[c] ----------------
__global__ __launch_bounds__(256) void gather2_kernel(const int* __restrict__ rowptr,
                                                      const int* __restrict__ csr_src,
                                                      const __half* __restrict__ zh,
                                                      const float* __restrict__ W2,
                                                      const float* __restrict__ b2,
                                                      const float* __restrict__ dinv,
                                                      float* __restrict__ out) {
    __shared__ float W2s[HID * NCLS];   // 640 floats
    __shared__ float b2s[NCLS];
    int t = threadIdx.x;
    for (int i = t; i < HID * NCLS; i += 256) W2s[i] = W2[i];
    if (t < NCLS) b2s[t] = b2[t];
    __syncthreads();

    int n   = blockIdx.x * 16 + (t >> 4);
    int sub = t & 15;
    const float4* tab = (const float4*)zh;
    int beg = rowptr[n], end = rowptr[n + 1];
    float acc[16];
    #pragma unroll
    for (int i = 0; i < 16; i++) acc[i] = 0.f;
    if (sub == 0) acc_row(tab, n, acc);               // self-loop
    for (int e = beg + sub; e < end; e += 16)
        acc_row(tab, csr_src[e], acc);
    #pragma unroll
    for (int m = 1; m < 16; m <<= 1) {
        #pragma unroll
        for (int i = 0; i < 16; i++) acc[i] += __shfl_xor(acc[i], m, 16);
    }
    if (sub < 10) {
        float dv = dinv[n];
        int c0 = sub * 4;
        float o0 = 0.f, o1 = 0.f, o2 = 0.f, o3 = 0.f;
        #pragma unroll
        for (int h = 0; h < HID; h++) {
            float a = acc[h];
            const float* w = &W2s[h * NCLS + c0];
            o0 += a * w[0]; o1 += a * w[1]; o2 += a * w[2]; o3 += a * w[3];
        }
        float4 r = make_float4(dv * o0 + b2s[c0],     dv * o1 + b2s[c0 + 1],
                               dv * o2 + b2s[c0 + 2], dv * o3 + b2s[c0 + 3]);
        *(float4*)(out + (size_t)n * NCLS + c0) = r;
    }
}

extern "C" void kernel_launch(void* const* d_in, const int* in_sizes, int n_in,
                              void* d_out, int out_size, void* d_ws, size_t ws_size,
                              hipStream_t stream) {
    const float* x   = (const float*)d_in[0];
    const int*   ei  = (const int*)  d_in[1];   // [2, E] int32
    const float* W1  = (const float*)d_in[2];
    const float* b1  = (const float*)d_in[3];
    const float* W2  = (const float*)d_in[4];
    const float* b2  = (const float*)d_in[5];
    float* out = (float*)d_out;

    char* ws = (char*)d_ws;
    size_t off = 0;
    int*   hist_blk    = (int*)(ws + off); off += (size_t)NB2 * NBLK * 4;       // 154 KB
    int*   rowsum      = (int*)(ws + off); off += (size_t)NB2 * 4;
    int*   bucket_base = (int*)(ws + off); off += (size_t)NB2 * 4;
    off = (off + 15) & ~(size_t)15;
    int*    rowptr  = (int*)   (ws + off); off += (size_t)(N_NODES + 1) * 4;
    off = (off + 15) & ~(size_t)15;
    float*  dinv    = (float*) (ws + off); off += (size_t)N_NODES * 4;
    int*    csr_src = (int*)   (ws + off); off += (size_t)N_EDGES * 4;          // 12.8 MB
    int*    buf     = (int*)   (ws + off); off += (size_t)N_EDGES * 4;          // 12.8 MB
    __half* y1h     = (__half*)(ws + off); off += (size_t)N_NODES * HID * 2;    //  3.2 MB
    __half* zh      = (__half*)(ws + off); off += (size_t)N_NODES * HID * 2;    //  3.2 MB

    hist_kernel    <<<NBLK, 256, 0, stream>>>(ei, hist_blk);
    rowscan_kernel <<<NB2, 256, 0, stream>>>(hist_blk, rowsum);
    basescan_kernel<<<1, 256, 0, stream>>>(rowsum, bucket_base);
    bin2_kernel    <<<NBLK, 256, 0, stream>>>(ei, hist_blk, bucket_base, buf);
    build_kernel   <<<NB2, 512, 0, stream>>>(buf, bucket_base, rowsum, rowptr, dinv, csr_src);

    gemm1_kernel  <<<(N_NODES + 255) / 256, 256, 0, stream>>>(x, W1, dinv, y1h);
    gather1_kernel<<<N_NODES / 16, 256, 0, stream>>>(rowptr, csr_src, y1h, b1, dinv, zh);
    gather2_kernel<<<N_NODES / 16, 256, 0, stream>>>(rowptr, csr_src, zh, W2, b2, dinv, out);
}